// Round 1
// 279.144 us; speedup vs baseline: 1.0065x; 1.0065x over previous
//
#include <hip/hip_runtime.h>
#include <hip/hip_bf16.h>

#define DIN    4096
#define DOUT   11008
#define TM     64
#define KSPLIT 4
#define KCHUNK (DIN / KSPLIT)     // 1024
#define NCHUNKS (DOUT / 16)       // 688

typedef __attribute__((ext_vector_type(8))) short  bf16x8;
typedef __attribute__((ext_vector_type(4))) float  f32x4;

// floor(log2(safe_amax)) - 2, clipped; scale and 1/scale are powers of 2 (exact)
__device__ inline void mx_block_scale(float amax, float& scale, float& inv_scale) {
    float safe = amax > 0.0f ? amax : 1.0f;
    int e  = (int)((__float_as_uint(safe) >> 23) & 255) - 127; // floor(log2), normals
    int se = e - 2;
    if (se < -127) se = -127;       // E8M0_MIN clip (upper clip unreachable)
    scale     = ldexpf(1.0f, se);
    inv_scale = ldexpf(1.0f, -se);
}

// E2M1 quant-dequant of one element given the block scale (exact vs jnp ref).
// step = 2^(clamp(floor(log2 a),0,2)-1) computed via exponent-field clamp:
// a <= 6 so the upper clamp is free; lower clamp = integer max with 1.0f bits.
// Saves 2 cmp + 4 cndmask -> and + max + 2 int-subs vs the compare version.
__device__ inline float mx_qd(float v, float scale, float inv_scale) {
    float a = fabsf(v) * inv_scale;  // exact pow2 mult
    a = fminf(a, 6.0f);              // FP4_MAX saturate
    unsigned ebc = __float_as_uint(a) & 0x7f800000u;
    ebc = ebc < 0x3f800000u ? 0x3f800000u : ebc;       // e in {0,1,2}
    float step  = __uint_as_float(ebc - 0x00800000u);  // 2^(e-1): 0.5/1/2
    float rstep = __uint_as_float(0x7f800000u - ebc);  // 2^(1-e): 2/1/0.5
    float q = rintf(a * rstep) * step;   // round-half-even = jnp.round
    return copysignf(q * scale, v);
}

__device__ inline short bf16_trunc(float f) {
    // dequantized values have <=2 mantissa bits -> truncation exact
    return (short)(__float_as_uint(f) >> 16);
}

__device__ inline float blk_absmax8(const float4& a, const float4& b) {
    return fmaxf(fmaxf(fmaxf(fabsf(a.x), fabsf(a.y)), fmaxf(fabsf(a.z), fabsf(a.w))),
                 fmaxf(fmaxf(fabsf(b.x), fabsf(b.y)), fmaxf(fabsf(b.z), fabsf(b.w))));
}

// ---------------- kernel 1: quantize x -> bf16 in ws (exact) ----------------
__global__ __launch_bounds__(256) void quant_x_kernel(const float* __restrict__ x,
                                                      unsigned short* __restrict__ x_dq) {
    int gid = blockIdx.x * 256 + threadIdx.x;       // 65536 threads x 4 elems
    const float4 v = *(const float4*)(x + (size_t)gid * 4);
    float am = fmaxf(fmaxf(fabsf(v.x), fabsf(v.y)), fmaxf(fabsf(v.z), fabsf(v.w)));
    am = fmaxf(am, __shfl_xor(am, 1));
    am = fmaxf(am, __shfl_xor(am, 2));
    am = fmaxf(am, __shfl_xor(am, 4));              // 8-lane group = one 32-block
    float scale, inv;
    mx_block_scale(am, scale, inv);
    ushort4 q;
    q.x = (unsigned short)bf16_trunc(mx_qd(v.x, scale, inv));
    q.y = (unsigned short)bf16_trunc(mx_qd(v.y, scale, inv));
    q.z = (unsigned short)bf16_trunc(mx_qd(v.z, scale, inv));
    q.w = (unsigned short)bf16_trunc(mx_qd(v.w, scale, inv));
    *(ushort4*)(x_dq + (size_t)gid * 4) = q;
}

// ---------- kernel 2: fused W-quant GEMM + K-split reduce + bias ----------
// Block = 16 output cols (nch = blockIdx.x); wave w = K-split w (1024 elems).
// Main loop identical to the verified barrier-free version (same MFMA order).
// Epilogue: each wave drops its 64x16 partial into LDS, one barrier, then the
// 4 splits are summed in the SAME order the old reduce kernel used
// (((p0+p1)+p2)+p3) and quantized bias is added -> bit-identical output,
// but the 11.25 MB partial write + 11.25 MB re-read and the 3rd launch vanish.
__global__ __launch_bounds__(256) void gemm_fused_kernel(const unsigned short* __restrict__ x_dq,
                                                         const float* __restrict__ wgt,
                                                         const float* __restrict__ bias,
                                                         float* __restrict__ out) {
    const int lane  = threadIdx.x & 63;
    const int wid   = threadIdx.x >> 6;             // K-split 0..3
    const int nch   = blockIdx.x;                   // 0..687
    const int nlo   = lane & 15;
    const int kq    = lane >> 4;                    // quad 0..3
    const int kbase = wid * KCHUNK + kq * 8;

    __shared__ float red[KSPLIT][TM][20];           // pad 20: 2-way max (free)
    __shared__ float bq[32];

    // quantized bias for this block's 32-wide MXFP block (cols nch*16..+15
    // are one aligned half of bias block nch>>1). Wave-0 lanes 0..31 only;
    // xor partners (1,2,4,8,16) stay inside the active half-wave.
    if (threadIdx.x < 32) {
        float v = bias[(nch >> 1) * 32 + threadIdx.x];
        float am = fabsf(v);
        am = fmaxf(am, __shfl_xor(am, 1));
        am = fmaxf(am, __shfl_xor(am, 2));
        am = fmaxf(am, __shfl_xor(am, 4));
        am = fmaxf(am, __shfl_xor(am, 8));
        am = fmaxf(am, __shfl_xor(am, 16));
        float scale, inv;
        mx_block_scale(am, scale, inv);
        bq[threadIdx.x] = mx_qd(v, scale, inv);
    }

    const float*          wp = wgt  + (size_t)(nch * 16 + nlo) * DIN + kbase;
    const unsigned short* xp = x_dq + (size_t)nlo * DIN + kbase;

    f32x4 acc0 = {0.f,0.f,0.f,0.f};
    f32x4 acc1 = {0.f,0.f,0.f,0.f};
    f32x4 acc2 = {0.f,0.f,0.f,0.f};
    f32x4 acc3 = {0.f,0.f,0.f,0.f};

    // pipeline prologue: wa = W(k), wb = W(k+32) in flight, scale for wa ready
    float4 wa0 = *(const float4*)(wp);
    float4 wa1 = *(const float4*)(wp + 4);
    float4 wb0 = *(const float4*)(wp + 32);
    float4 wb1 = *(const float4*)(wp + 36);
    float am = blk_absmax8(wa0, wa1);
    am = fmaxf(am, __shfl_xor(am, 16));
    am = fmaxf(am, __shfl_xor(am, 32));
    float scale, inv;
    mx_block_scale(am, scale, inv);

    #pragma unroll 4
    for (int kk = 0; kk < KCHUNK; kk += 32) {
        // issue W(k+64); clamp keeps the last iterations in-bounds (dup load)
        const int kpre = (kk + 64 < KCHUNK) ? kk + 64 : KCHUNK - 32;
        float4 wc0 = *(const float4*)(wp + kpre);
        float4 wc1 = *(const float4*)(wp + kpre + 4);

        // A fragments (x_dq is 512 KB, L1/L2-resident)
        bf16x8 a0 = *(const bf16x8*)(xp + kk);
        bf16x8 a1 = *(const bf16x8*)(xp + 16 * DIN + kk);
        bf16x8 a2 = *(const bf16x8*)(xp + 32 * DIN + kk);
        bf16x8 a3 = *(const bf16x8*)(xp + 48 * DIN + kk);

        // quantize current tile with the pre-computed scale
        bf16x8 bf;
        bf[0] = bf16_trunc(mx_qd(wa0.x, scale, inv));
        bf[1] = bf16_trunc(mx_qd(wa0.y, scale, inv));
        bf[2] = bf16_trunc(mx_qd(wa0.z, scale, inv));
        bf[3] = bf16_trunc(mx_qd(wa0.w, scale, inv));
        bf[4] = bf16_trunc(mx_qd(wa1.x, scale, inv));
        bf[5] = bf16_trunc(mx_qd(wa1.y, scale, inv));
        bf[6] = bf16_trunc(mx_qd(wa1.z, scale, inv));
        bf[7] = bf16_trunc(mx_qd(wa1.w, scale, inv));

        acc0 = __builtin_amdgcn_mfma_f32_16x16x32_bf16(a0, bf, acc0, 0, 0, 0);
        acc1 = __builtin_amdgcn_mfma_f32_16x16x32_bf16(a1, bf, acc1, 0, 0, 0);
        acc2 = __builtin_amdgcn_mfma_f32_16x16x32_bf16(a2, bf, acc2, 0, 0, 0);
        acc3 = __builtin_amdgcn_mfma_f32_16x16x32_bf16(a3, bf, acc3, 0, 0, 0);

        // scale for the NEXT tile (wb arrived long ago); shfl latency overlaps
        // the MFMAs just issued
        float amn = blk_absmax8(wb0, wb1);
        amn = fmaxf(amn, __shfl_xor(amn, 16));
        amn = fmaxf(amn, __shfl_xor(amn, 32));
        mx_block_scale(amn, scale, inv);

        wa0 = wb0; wa1 = wb1;
        wb0 = wc0; wb1 = wc1;
    }

    // C/D map: col(n)=lane&15, row(m)=quad*4+reg (verified: absmax 0)
    const int mrow = kq * 4;
    #pragma unroll
    for (int r = 0; r < 4; ++r) {
        red[wid][mrow + r][nlo]      = acc0[r];
        red[wid][16 + mrow + r][nlo] = acc1[r];
        red[wid][32 + mrow + r][nlo] = acc2[r];
        red[wid][48 + mrow + r][nlo] = acc3[r];
    }
    __syncthreads();

    // 4 outputs per thread; split-sum order identical to old reduce kernel
    const int col  = threadIdx.x & 15;
    const int row0 = threadIdx.x >> 4;              // 0..15
    const float b  = bq[((nch & 1) << 4) + col];
    float* op = out + (size_t)nch * 16 + col;
    #pragma unroll
    for (int t = 0; t < 4; ++t) {
        const int row = row0 + 16 * t;
        float s = ((red[0][row][col] + red[1][row][col]) + red[2][row][col]) + red[3][row][col];
        op[(size_t)row * DOUT] = s + b;
    }
}

extern "C" void kernel_launch(void* const* d_in, const int* in_sizes, int n_in,
                              void* d_out, int out_size, void* d_ws, size_t ws_size,
                              hipStream_t stream) {
    const float* x    = (const float*)d_in[0];   // [64, 4096]
    const float* wgt  = (const float*)d_in[1];   // [11008, 4096]
    const float* bias = (const float*)d_in[2];   // [11008]
    float* out = (float*)d_out;                  // [64, 11008]

    unsigned short* x_dq = (unsigned short*)d_ws;    // 512 KB (only ws use now)

    quant_x_kernel<<<256, 256, 0, stream>>>(x, x_dq);
    gemm_fused_kernel<<<NCHUNKS, 256, 0, stream>>>(x_dq, wgt, bias, out);
}